// Round 15
// baseline (161.090 us; speedup 1.0000x reference)
//
#include <hip/hip_runtime.h>
#include <stdint.h>

#define L2E 1.44269504088896340736f

typedef _Float16 half8 __attribute__((ext_vector_type(8)));
typedef float floatx4 __attribute__((ext_vector_type(4)));

static __device__ __forceinline__ unsigned short f32_to_f16u(float f) {
  union { _Float16 h; unsigned short s; } cv; cv.h = (_Float16)f; return cv.s;
}

// raw hardware exp2 (no ocml wrapper); inputs here are small (|x| < 16)
static __device__ __forceinline__ float fast_exp2(float x) {
  float r;
  asm("v_exp_f32 %0, %1" : "=v"(r) : "v"(x));
  return r;
}

typedef __attribute__((address_space(3))) unsigned int as3_uint;
typedef __attribute__((address_space(1))) const unsigned int as1_cuint;

// async global->LDS, 16B per lane; HW dest = wave-uniform base + lane*16
static __device__ __forceinline__ void async16(const void* g, void* l) {
  __builtin_amdgcn_global_load_lds((as1_cuint*)g, (as3_uint*)l, 16, 0, 0);
}

// ---------------------------------------------------------------------------
// Projection GEMM:  outT[n][o] = sum_c X[c][n]*W[o][c] + b[o]
// X tile [256 c][64 n] staged to LDS fp16 (pitch 76) via COALESCED float4
// reads. A-frags hoisted once per block -- after which sX is DEAD, so the
// W subtile buffer ALIASES sX's storage (LDS 38.9KB -> 4 blocks/CU).
// z=0: s=0 -> q (Wq), s=1 -> k (Wk), from depth.
// z=1,2: 4 subtiles of 32 co each, v from rgb.
// ---------------------------------------------------------------------------
__global__ __launch_bounds__(256) void proj_kernel(
    const float* __restrict__ rgb,
    const float* __restrict__ depth,
    const float* __restrict__ Wq, const float* __restrict__ bq,
    const float* __restrict__ Wk, const float* __restrict__ bk,
    const float* __restrict__ Wv, const float* __restrict__ bv,
    unsigned short* __restrict__ qT,
    unsigned short* __restrict__ kT,
    unsigned short* __restrict__ v)
{
  __shared__ __align__(16) unsigned short sX[256 * 76];  // 38912 B total LDS
  unsigned short* sW = sX;  // W subtile (16 KB) overlays sX -- dead after hoist

  const int n0 = blockIdx.x * 64;
  const int b  = blockIdx.y;
  const int z  = blockIdx.z;
  const int t  = threadIdx.x;
  const int w  = t >> 6;
  const int lane = t & 63;
  const int l15 = lane & 15;
  const int q4  = lane >> 4;

  const float* X = (z == 0) ? depth : rgb;
  const float* xb = X + (size_t)b * 256 * 4096 + n0;

  // ---- stage X tile: 2048 half8-chunks; chunk h: c = h>>3, n-octet = h&7
#pragma unroll
  for (int i = 0; i < 8; i++) {
    int h = i * 256 + t;
    int c = h >> 3, oct = h & 7;
    const float* src = xb + (size_t)c * 4096 + oct * 8;
    float4 x0 = *(const float4*)src;
    float4 x1 = *(const float4*)(src + 4);
    half8 hh;
    hh[0] = (_Float16)x0.x; hh[1] = (_Float16)x0.y; hh[2] = (_Float16)x0.z; hh[3] = (_Float16)x0.w;
    hh[4] = (_Float16)x1.x; hh[5] = (_Float16)x1.y; hh[6] = (_Float16)x1.z; hh[7] = (_Float16)x1.w;
    *(half8*)&sX[c * 76 + oct * 8] = hh;
  }
  __syncthreads();

  // ---- hoist A-frags once (reused across all subtiles); sX dead afterwards
  half8 a8[8];
#pragma unroll
  for (int ks = 0; ks < 8; ks++) {
#pragma unroll
    for (int j = 0; j < 8; j++) {
      a8[ks][j] = *(const _Float16*)&sX[(ks * 32 + q4 * 8 + j) * 76 + 16 * w + l15];
    }
  }

  const int ns = (z == 0) ? 2 : 4;
  for (int s = 0; s < ns; s++) {
    const int colbase = (z == 0) ? 0 : (z - 1) * 128 + s * 32;
    __syncthreads();  // prev subtile's LDS reads (and the a8 hoist) done

    // ---- stage W subtile (32 o x 256 c): 1024 16B-chunks, swizzled
#pragma unroll
    for (int i = 0; i < 4; i++) {
      int L = i * 256 + t;
      int og = L >> 5;
      int phys = L & 31;
      int ci = phys ^ (og & 7);
      const float* wr;
      if (z == 0) wr = ((s == 0) ? Wq : Wk) + (size_t)og * 256;
      else        wr = Wv + (size_t)(colbase + og) * 256;
      float4 w0 = *(const float4*)(wr + ci * 8);
      float4 w1 = *(const float4*)(wr + ci * 8 + 4);
      half8 h;
      h[0] = (_Float16)w0.x; h[1] = (_Float16)w0.y; h[2] = (_Float16)w0.z; h[3] = (_Float16)w0.w;
      h[4] = (_Float16)w1.x; h[5] = (_Float16)w1.y; h[6] = (_Float16)w1.z; h[7] = (_Float16)w1.w;
      *(half8*)&sW[(size_t)L * 8] = h;
    }

    float bias2[2];
#pragma unroll
    for (int ct = 0; ct < 2; ct++) {
      int og = ct * 16 + l15;
      if (z == 0) bias2[ct] = (s == 0) ? bq[og] : bk[og];
      else        bias2[ct] = bv[colbase + og];
    }
    __syncthreads();

    floatx4 acc2[2];
    acc2[0] = (floatx4){0.f, 0.f, 0.f, 0.f};
    acc2[1] = (floatx4){0.f, 0.f, 0.f, 0.f};

#pragma unroll
    for (int ks = 0; ks < 8; ks++) {
      const int ci = ks * 4 + q4;
#pragma unroll
      for (int ct = 0; ct < 2; ct++) {
        int og = ct * 16 + l15;
        half8 bf = *(const half8*)&sW[og * 256 + ((ci ^ (og & 7)) * 8)];
        acc2[ct] = __builtin_amdgcn_mfma_f32_16x16x32_f16(a8[ks], bf, acc2[ct], 0, 0, 0);
      }
    }

    __syncthreads();  // done reading sW before epilogue reuse / next stage

    if (z == 0) {
#pragma unroll
      for (int ct = 0; ct < 2; ct++) {
        int og = ct * 16 + l15;
#pragma unroll
        for (int r = 0; r < 4; r++) {
          int n = n0 + 16 * w + q4 * 4 + r;
          unsigned short hv = f32_to_f16u(acc2[ct][r] + bias2[ct]);
          if (s == 0) qT[((size_t)b * 4096 + n) * 32 + og] = hv;
          else        kT[((size_t)b * 4096 + n) * 32 + og] = hv;
        }
      }
    } else {
      unsigned short* tile = sW;  // reuse: [32 co][pitch 72]
#pragma unroll
      for (int ct = 0; ct < 2; ct++) {
#pragma unroll
        for (int r = 0; r < 4; r++) {
          int co_l = ct * 16 + l15;
          int nl = 16 * w + q4 * 4 + r;
          tile[co_l * 72 + nl] = f32_to_f16u(acc2[ct][r] + bias2[ct]);
        }
      }
      __syncthreads();
      {
        int co_l = t >> 3;
        int ch = t & 7;
        int4 val = *(const int4*)&tile[co_l * 72 + ch * 8];
        *(int4*)&v[((size_t)b * 256 + colbase + co_l) * 4096 + n0 + ch * 8] = val;
      }
    }
  }
}

// ---------------------------------------------------------------------------
// V staging: [256 co][32 m] fp16, phys chunk p of row c holds logical
// p ^ ((c>>1)&3); pre-swizzled global source + LINEAR LDS dest (the
// global_load_lds contract: wave-uniform base + lane*16).
// ---------------------------------------------------------------------------
static __device__ __forceinline__ void stage_v(
    const unsigned short* __restrict__ vB, unsigned char* sbase,
    int m0, int t, int w)
{
#pragma unroll
  for (int j = 0; j < 4; j++) {
    int lin = j * 256 + t;
    int c = lin >> 2;
    int p = lin & 3;
    int lc = p ^ ((c >> 1) & 3);
    async16(&vB[(size_t)c * 4096 + m0 + lc * 8], sbase + j * 4096 + w * 1024);
  }
}

// ---------------------------------------------------------------------------
// Flash attention, split-m (best-measured structure + split-wait reorder):
// S phase: waves split by n. PV phase: waves split by co. V double-buffered
// via global_load_lds, K prefetched to regs. Per iter: issue K(i+1) FIRST,
// then stage_v(i+1) -- so the compiler's dependency wait before QK(i)
// completes only K(i) (vmcnt(10)), and the explicit vmcnt(6) that
// guarantees stage(i) landed sits AFTER the QK/exp/pack VALU phase, just
// before the barrier: the V-tile tail latency overlaps register-only work
// instead of preceding it. fast_exp2 for softmax exp.
// XCD swizzle: o = blockIdx.x; all 64 n-blocks of one (b,chunk) -> same XCD.
// ---------------------------------------------------------------------------
__global__ __launch_bounds__(256, 4) void attn_kernel(
    const unsigned short* __restrict__ qT,  // [b][n][32] fp16
    const unsigned short* __restrict__ kT,  // [b][m][32] fp16
    const unsigned short* __restrict__ v,   // [b][co][m] fp16
    unsigned short* __restrict__ Op,        // [chunk][b][co][n] fp16 (unnormalized)
    float* __restrict__ lW)                 // [chunk][b][n]
{
  __shared__ __align__(16) unsigned char smem[37888];
  // sV buf0: [0,16384), buf1: [16384,32768)  -- [256 co][32 m] fp16 swizzled
  // sP: [32768, 37888) -- [64 n][pitch 40] u16 (wave w owns rows 16w..16w+15)
  unsigned short* sP = (unsigned short*)(smem + 32768);

  const int o = blockIdx.x;
  const int n0 = ((o >> 3) & 63) * 64;
  const int p  = (o & 7) | ((o >> 9) << 3);
  const int b  = p & 3;
  const int chunk = p >> 2;
  const int t  = threadIdx.x;
  const int w  = t >> 6;
  const int lane = t & 63;
  const int l15 = lane & 15;
  const int q4  = lane >> 4;

  half8 aq = *(const half8*)(qT + ((size_t)b * 4096 + n0 + 16 * w + l15) * 32 + q4 * 8);

  const unsigned short* vB = v + (size_t)b * 256 * 4096;
  const unsigned short* kL = kT + (size_t)b * 4096 * 32 + (size_t)l15 * 32 + q4 * 8;
  unsigned short* sPw = sP + w * 640;

  float lsum[4] = {0.f, 0.f, 0.f, 0.f};
  floatx4 acc[16];  // [ct co-tile][nt n-tile] -> acc[ct*4+nt]
#pragma unroll
  for (int ct = 0; ct < 16; ct++) acc[ct] = (floatx4){0.f, 0.f, 0.f, 0.f};
  const floatx4 zf = (floatx4){0.f, 0.f, 0.f, 0.f};

  const int mbase = chunk * 1024;

  // prologue: K(0) first, then V(0) -> buf0 (K oldest => cheap QK wait)
  half8 kc0 = *(const half8*)(kL + (size_t)mbase * 32);
  half8 kc1 = *(const half8*)(kL + (size_t)(mbase + 16) * 32);
  stage_v(vB, smem, mbase, t, w);

  int bufoff = 0;
  for (int it = 0; it < 32; ++it) {
    const int m0 = mbase + it * 32;
    half8 kn0 = kc0, kn1 = kc1;
    if (it < 31) {
      // K(i+1) FIRST, then stage(i+1): QK(i)'s compiler wait on K(i)
      // (oldest outstanding) no longer forces stage(i) completion.
      kn0 = *(const half8*)(kL + (size_t)(m0 + 32) * 32);
      kn1 = *(const half8*)(kL + (size_t)(m0 + 48) * 32);
      stage_v(vB, smem + (bufoff ^ 16384), m0 + 32, t, w);
    }

    // S = Q K^T for this wave's 16 n x 32 m (K in regs; compiler inserts
    // the counted vmcnt for kc use -- only K(i) must land here)
    floatx4 s0 = __builtin_amdgcn_mfma_f32_16x16x32_f16(aq, kc0, zf, 0, 0, 0);
    floatx4 s1 = __builtin_amdgcn_mfma_f32_16x16x32_f16(aq, kc1, zf, 0, 0, 0);

    float p0[4], p1[4];
#pragma unroll
    for (int r = 0; r < 4; r++) {
      p0[r] = fast_exp2(s0[r] * L2E);
      p1[r] = fast_exp2(s1[r] * L2E);
      lsum[r] += p0[r] + p1[r];
    }
#pragma unroll
    for (int r = 0; r < 4; r++) {
      int row = q4 * 4 + r;
      sPw[row * 40 + l15]      = f32_to_f16u(p0[r]);
      sPw[row * 40 + 16 + l15] = f32_to_f16u(p1[r]);
    }
    asm volatile("s_waitcnt lgkmcnt(0)" ::: "memory");  // own P writes visible

    // stage(i) landed (overlapped the QK/exp/pack phase above):
    // leave the 6 newest (K(i+1) 2 + stage(i+1) 4) in flight.
    if (it < 31) asm volatile("s_waitcnt vmcnt(6)" ::: "memory");
    else         asm volatile("s_waitcnt vmcnt(0)" ::: "memory");

    // barrier: all P written, all V(it) landed
    __builtin_amdgcn_s_barrier();
    asm volatile("s_waitcnt lgkmcnt(0)" ::: "memory");  // fence: no read hoist

    // P-frags for ALL 64 n (rows nt*16+l15, k = m = q4*8+j)
    half8 ap[4];
#pragma unroll
    for (int nt = 0; nt < 4; nt++)
      ap[nt] = *(const half8*)&sP[nt * 640 + l15 * 40 + q4 * 8];

    const unsigned short* sVb = (const unsigned short*)(smem + bufoff);
#pragma unroll
    for (int ct = 0; ct < 4; ct++) {
      int co = w * 64 + ct * 16 + l15;
      half8 bv8 = *(const half8*)&sVb[co * 32 + ((q4 ^ ((co >> 1) & 3)) * 8)];
#pragma unroll
      for (int nt = 0; nt < 4; nt++)
        acc[ct * 4 + nt] = __builtin_amdgcn_mfma_f32_16x16x32_f16(ap[nt], bv8, acc[ct * 4 + nt], 0, 0, 0);
    }
    asm volatile("s_waitcnt lgkmcnt(0)" ::: "memory");  // reads done before reuse
    __builtin_amdgcn_s_barrier();

    kc0 = kn0; kc1 = kn1;
    bufoff ^= 16384;
  }

  // lsum reduce (S phase split by n: wave w owns rows n0+16w+..)
#pragma unroll
  for (int off = 1; off < 16; off <<= 1) {
#pragma unroll
    for (int r = 0; r < 4; r++) lsum[r] += __shfl_xor(lsum[r], off);
  }
  if (l15 == 0) {
#pragma unroll
    for (int r = 0; r < 4; r++)
      lW[((size_t)chunk * 4 + b) * 4096 + n0 + 16 * w + q4 * 4 + r] = lsum[r];
  }

  // epilogue: wave w owns co w*64..w*64+63, all 64 n.
  unsigned short* sO = (unsigned short*)smem;  // [128 co][pitch 72]
#pragma unroll
  for (int pass = 0; pass < 2; pass++) {
    __syncthreads();
    if ((w >> 1) == pass) {
#pragma unroll
      for (int ct = 0; ct < 4; ct++) {
        int co_l = (w & 1) * 64 + ct * 16 + l15;
#pragma unroll
        for (int nt = 0; nt < 4; nt++) {
#pragma unroll
          for (int r = 0; r < 4; r++) {
            int nl = nt * 16 + q4 * 4 + r;
            sO[co_l * 72 + nl] = f32_to_f16u(acc[ct * 4 + nt][r]);
          }
        }
      }
    }
    __syncthreads();
#pragma unroll
    for (int s = 0; s < 4; s++) {
      int co_l = s * 32 + (t >> 3);
      int ch = t & 7;
      int4 val = *(const int4*)&sO[co_l * 72 + ch * 8];
      *(int4*)&Op[(((size_t)chunk * 4 + b) * 256 + pass * 128 + co_l) * 4096 + n0 + ch * 8] = val;
    }
  }
}

// ---------------------------------------------------------------------------
// Combine: out[b][co][n] = sum_ch Op[ch][b][co][n] / sum_ch lW[ch][b][n]
// ---------------------------------------------------------------------------
__global__ __launch_bounds__(256) void combine_kernel(
    const unsigned short* __restrict__ Op,
    const float* __restrict__ lW,
    float* __restrict__ out)
{
  const int t = threadIdx.x;
  const int b = blockIdx.y;
  const size_t n8 = (size_t)blockIdx.x * 2048 + (size_t)t * 8;
  const int co0 = blockIdx.z * 4;

  float sum[8] = {0.f, 0.f, 0.f, 0.f, 0.f, 0.f, 0.f, 0.f};
#pragma unroll
  for (int ch = 0; ch < 4; ch++) {
    const float* lp = lW + ((size_t)ch * 4 + b) * 4096 + n8;
    float4 a0 = *(const float4*)lp;
    float4 a1 = *(const float4*)(lp + 4);
    sum[0] += a0.x; sum[1] += a0.y; sum[2] += a0.z; sum[3] += a0.w;
    sum[4] += a1.x; sum[5] += a1.y; sum[6] += a1.z; sum[7] += a1.w;
  }
  float rl[8];
#pragma unroll
  for (int i = 0; i < 8; i++) rl[i] = 1.0f / sum[i];

#pragma unroll
  for (int cc = 0; cc < 4; cc++) {
    int co = co0 + cc;
    float o[8] = {0.f, 0.f, 0.f, 0.f, 0.f, 0.f, 0.f, 0.f};
#pragma unroll
    for (int ch = 0; ch < 4; ch++) {
      half8 hv = *(const half8*)&Op[(((size_t)ch * 4 + b) * 256 + co) * 4096 + n8];
#pragma unroll
      for (int i = 0; i < 8; i++) o[i] += (float)hv[i];
    }
    float* op = out + ((size_t)b * 256 + co) * 4096 + n8;
    float4 r0, r1;
    r0.x = o[0] * rl[0]; r0.y = o[1] * rl[1]; r0.z = o[2] * rl[2]; r0.w = o[3] * rl[3];
    r1.x = o[4] * rl[4]; r1.y = o[5] * rl[5]; r1.z = o[6] * rl[6]; r1.w = o[7] * rl[7];
    *(float4*)op = r0;
    *(float4*)(op + 4) = r1;
  }
}

extern "C" void kernel_launch(void* const* d_in, const int* in_sizes, int n_in,
                              void* d_out, int out_size, void* d_ws, size_t ws_size,
                              hipStream_t stream) {
  const float* rgb   = (const float*)d_in[0];
  const float* depth = (const float*)d_in[1];
  const float* Wq    = (const float*)d_in[2];
  const float* bq    = (const float*)d_in[3];
  const float* Wk    = (const float*)d_in[4];
  const float* bk    = (const float*)d_in[5];
  const float* Wv    = (const float*)d_in[6];
  const float* bv    = (const float*)d_in[7];
  float* out = (float*)d_out;

  unsigned short* qT = (unsigned short*)d_ws;             // 1 MB
  unsigned short* kT = qT + (size_t)4 * 4096 * 32;        // 1 MB
  unsigned short* vW = kT + (size_t)4 * 4096 * 32;        // 8 MB
  unsigned short* Op = vW + (size_t)4 * 256 * 4096;       // 33.5 MB (4 chunks)
  float* lW = (float*)(Op + (size_t)4 * 4 * 256 * 4096);  // 256 KB

  dim3 pg(64, 4, 3);
  proj_kernel<<<pg, 256, 0, stream>>>(rgb, depth, Wq, bq, Wk, bk, Wv, bv, qT, kT, vW);
  attn_kernel<<<dim3(1024, 1, 1), 256, 0, stream>>>(qT, kT, vW, Op, lW);
  dim3 cg(2, 4, 64);
  combine_kernel<<<cg, 256, 0, stream>>>(Op, lW, out);
}

// Round 16
// 159.518 us; speedup vs baseline: 1.0099x; 1.0099x over previous
//
#include <hip/hip_runtime.h>
#include <stdint.h>

#define L2E 1.44269504088896340736f

typedef _Float16 half8 __attribute__((ext_vector_type(8)));
typedef float floatx4 __attribute__((ext_vector_type(4)));

static __device__ __forceinline__ unsigned short f32_to_f16u(float f) {
  union { _Float16 h; unsigned short s; } cv; cv.h = (_Float16)f; return cv.s;
}

// raw hardware exp2 (no ocml wrapper); inputs here are small (|x| < 16)
static __device__ __forceinline__ float fast_exp2(float x) {
  float r;
  asm("v_exp_f32 %0, %1" : "=v"(r) : "v"(x));
  return r;
}

typedef __attribute__((address_space(3))) unsigned int as3_uint;
typedef __attribute__((address_space(1))) const unsigned int as1_cuint;

// async global->LDS, 16B per lane; HW dest = wave-uniform base + lane*16
static __device__ __forceinline__ void async16(const void* g, void* l) {
  __builtin_amdgcn_global_load_lds((as1_cuint*)g, (as3_uint*)l, 16, 0, 0);
}

// ---------------------------------------------------------------------------
// Projection GEMM:  outT[n][o] = sum_c X[c][n]*W[o][c] + b[o]
// X tile [256 c][64 n] staged to LDS fp16 (pitch 76) via COALESCED float4
// reads. A-frags hoisted once per block -- after which sX is DEAD, so the
// W subtile buffer ALIASES sX's storage: LDS block 55.3KB -> 38.9KB,
// 2 -> 4 blocks/CU capacity => the whole 768-block grid resident in one
// round instead of two. W staged in 32-row subtiles.
// z=0: s=0 -> q (Wq), s=1 -> k (Wk), from depth.
// z=1,2: 4 subtiles of 32 co each, v from rgb.
// ---------------------------------------------------------------------------
__global__ __launch_bounds__(256) void proj_kernel(
    const float* __restrict__ rgb,
    const float* __restrict__ depth,
    const float* __restrict__ Wq, const float* __restrict__ bq,
    const float* __restrict__ Wk, const float* __restrict__ bk,
    const float* __restrict__ Wv, const float* __restrict__ bv,
    unsigned short* __restrict__ qT,
    unsigned short* __restrict__ kT,
    unsigned short* __restrict__ v)
{
  __shared__ __align__(16) unsigned short sX[256 * 76];  // 38912 B total LDS
  unsigned short* sW = sX;  // W subtile (16 KB) overlays sX -- dead after hoist

  const int n0 = blockIdx.x * 64;
  const int b  = blockIdx.y;
  const int z  = blockIdx.z;
  const int t  = threadIdx.x;
  const int w  = t >> 6;
  const int lane = t & 63;
  const int l15 = lane & 15;
  const int q4  = lane >> 4;

  const float* X = (z == 0) ? depth : rgb;
  const float* xb = X + (size_t)b * 256 * 4096 + n0;

  // ---- stage X tile: 2048 half8-chunks; chunk h: c = h>>3, n-octet = h&7
#pragma unroll
  for (int i = 0; i < 8; i++) {
    int h = i * 256 + t;
    int c = h >> 3, oct = h & 7;
    const float* src = xb + (size_t)c * 4096 + oct * 8;
    float4 x0 = *(const float4*)src;
    float4 x1 = *(const float4*)(src + 4);
    half8 hh;
    hh[0] = (_Float16)x0.x; hh[1] = (_Float16)x0.y; hh[2] = (_Float16)x0.z; hh[3] = (_Float16)x0.w;
    hh[4] = (_Float16)x1.x; hh[5] = (_Float16)x1.y; hh[6] = (_Float16)x1.z; hh[7] = (_Float16)x1.w;
    *(half8*)&sX[c * 76 + oct * 8] = hh;
  }
  __syncthreads();

  // ---- hoist A-frags once (reused across all subtiles); sX dead afterwards
  half8 a8[8];
#pragma unroll
  for (int ks = 0; ks < 8; ks++) {
#pragma unroll
    for (int j = 0; j < 8; j++) {
      a8[ks][j] = *(const _Float16*)&sX[(ks * 32 + q4 * 8 + j) * 76 + 16 * w + l15];
    }
  }

  const int ns = (z == 0) ? 2 : 4;
  for (int s = 0; s < ns; s++) {
    const int colbase = (z == 0) ? 0 : (z - 1) * 128 + s * 32;
    __syncthreads();  // prev subtile's LDS reads (and the a8 hoist) done

    // ---- stage W subtile (32 o x 256 c): 1024 16B-chunks, swizzled
#pragma unroll
    for (int i = 0; i < 4; i++) {
      int L = i * 256 + t;
      int og = L >> 5;
      int phys = L & 31;
      int ci = phys ^ (og & 7);
      const float* wr;
      if (z == 0) wr = ((s == 0) ? Wq : Wk) + (size_t)og * 256;
      else        wr = Wv + (size_t)(colbase + og) * 256;
      float4 w0 = *(const float4*)(wr + ci * 8);
      float4 w1 = *(const float4*)(wr + ci * 8 + 4);
      half8 h;
      h[0] = (_Float16)w0.x; h[1] = (_Float16)w0.y; h[2] = (_Float16)w0.z; h[3] = (_Float16)w0.w;
      h[4] = (_Float16)w1.x; h[5] = (_Float16)w1.y; h[6] = (_Float16)w1.z; h[7] = (_Float16)w1.w;
      *(half8*)&sW[(size_t)L * 8] = h;
    }

    float bias2[2];
#pragma unroll
    for (int ct = 0; ct < 2; ct++) {
      int og = ct * 16 + l15;
      if (z == 0) bias2[ct] = (s == 0) ? bq[og] : bk[og];
      else        bias2[ct] = bv[colbase + og];
    }
    __syncthreads();

    floatx4 acc2[2];
    acc2[0] = (floatx4){0.f, 0.f, 0.f, 0.f};
    acc2[1] = (floatx4){0.f, 0.f, 0.f, 0.f};

#pragma unroll
    for (int ks = 0; ks < 8; ks++) {
      const int ci = ks * 4 + q4;
#pragma unroll
      for (int ct = 0; ct < 2; ct++) {
        int og = ct * 16 + l15;
        half8 bf = *(const half8*)&sW[og * 256 + ((ci ^ (og & 7)) * 8)];
        acc2[ct] = __builtin_amdgcn_mfma_f32_16x16x32_f16(a8[ks], bf, acc2[ct], 0, 0, 0);
      }
    }

    __syncthreads();  // done reading sW before epilogue reuse / next stage

    if (z == 0) {
#pragma unroll
      for (int ct = 0; ct < 2; ct++) {
        int og = ct * 16 + l15;
#pragma unroll
        for (int r = 0; r < 4; r++) {
          int n = n0 + 16 * w + q4 * 4 + r;
          unsigned short hv = f32_to_f16u(acc2[ct][r] + bias2[ct]);
          if (s == 0) qT[((size_t)b * 4096 + n) * 32 + og] = hv;
          else        kT[((size_t)b * 4096 + n) * 32 + og] = hv;
        }
      }
    } else {
      unsigned short* tile = sW;  // reuse: [32 co][pitch 72]
#pragma unroll
      for (int ct = 0; ct < 2; ct++) {
#pragma unroll
        for (int r = 0; r < 4; r++) {
          int co_l = ct * 16 + l15;
          int nl = 16 * w + q4 * 4 + r;
          tile[co_l * 72 + nl] = f32_to_f16u(acc2[ct][r] + bias2[ct]);
        }
      }
      __syncthreads();
      {
        int co_l = t >> 3;
        int ch = t & 7;
        int4 val = *(const int4*)&tile[co_l * 72 + ch * 8];
        *(int4*)&v[((size_t)b * 256 + colbase + co_l) * 4096 + n0 + ch * 8] = val;
      }
    }
  }
}

// ---------------------------------------------------------------------------
// V staging: [256 co][32 m] fp16, phys chunk p of row c holds logical
// p ^ ((c>>1)&3); pre-swizzled global source + LINEAR LDS dest (the
// global_load_lds contract: wave-uniform base + lane*16).
// ---------------------------------------------------------------------------
static __device__ __forceinline__ void stage_v(
    const unsigned short* __restrict__ vB, unsigned char* sbase,
    int m0, int t, int w)
{
#pragma unroll
  for (int j = 0; j < 4; j++) {
    int lin = j * 256 + t;
    int c = lin >> 2;
    int p = lin & 3;
    int lc = p ^ ((c >> 1) & 3);
    async16(&vB[(size_t)c * 4096 + m0 + lc * 8], sbase + j * 4096 + w * 1024);
  }
}

// ---------------------------------------------------------------------------
// Flash attention, split-m (best-measured configuration, locked in):
// S phase: waves split by n. PV phase: waves split by co. V double-buffered
// via global_load_lds, K prefetched to regs, counted vmcnt(6) so next-iter
// loads stay in flight across the barrier. fast_exp2 for softmax exp.
// XCD swizzle: o = blockIdx.x; all 64 n-blocks of one (b,chunk) -> same XCD.
// ---------------------------------------------------------------------------
__global__ __launch_bounds__(256, 4) void attn_kernel(
    const unsigned short* __restrict__ qT,  // [b][n][32] fp16
    const unsigned short* __restrict__ kT,  // [b][m][32] fp16
    const unsigned short* __restrict__ v,   // [b][co][m] fp16
    unsigned short* __restrict__ Op,        // [chunk][b][co][n] fp16 (unnormalized)
    float* __restrict__ lW)                 // [chunk][b][n]
{
  __shared__ __align__(16) unsigned char smem[37888];
  // sV buf0: [0,16384), buf1: [16384,32768)  -- [256 co][32 m] fp16 swizzled
  // sP: [32768, 37888) -- [64 n][pitch 40] u16 (wave w owns rows 16w..16w+15)
  unsigned short* sP = (unsigned short*)(smem + 32768);

  const int o = blockIdx.x;
  const int n0 = ((o >> 3) & 63) * 64;
  const int p  = (o & 7) | ((o >> 9) << 3);
  const int b  = p & 3;
  const int chunk = p >> 2;
  const int t  = threadIdx.x;
  const int w  = t >> 6;
  const int lane = t & 63;
  const int l15 = lane & 15;
  const int q4  = lane >> 4;

  half8 aq = *(const half8*)(qT + ((size_t)b * 4096 + n0 + 16 * w + l15) * 32 + q4 * 8);

  const unsigned short* vB = v + (size_t)b * 256 * 4096;
  const unsigned short* kL = kT + (size_t)b * 4096 * 32 + (size_t)l15 * 32 + q4 * 8;
  unsigned short* sPw = sP + w * 640;

  float lsum[4] = {0.f, 0.f, 0.f, 0.f};
  floatx4 acc[16];  // [ct co-tile][nt n-tile] -> acc[ct*4+nt]
#pragma unroll
  for (int ct = 0; ct < 16; ct++) acc[ct] = (floatx4){0.f, 0.f, 0.f, 0.f};
  const floatx4 zf = (floatx4){0.f, 0.f, 0.f, 0.f};

  const int mbase = chunk * 1024;

  // prologue: V(0) -> buf0, K(0) -> regs
  stage_v(vB, smem, mbase, t, w);
  half8 kc0 = *(const half8*)(kL + (size_t)mbase * 32);
  half8 kc1 = *(const half8*)(kL + (size_t)(mbase + 16) * 32);

  int bufoff = 0;
  for (int it = 0; it < 32; ++it) {
    const int m0 = mbase + it * 32;
    half8 kn0 = kc0, kn1 = kc1;
    if (it < 31) {
      // issue next-iter V stage (4) + K prefetch (2), then wait for THIS
      // iter's 6: allow the 6 just-issued to stay in flight.
      stage_v(vB, smem + (bufoff ^ 16384), m0 + 32, t, w);
      kn0 = *(const half8*)(kL + (size_t)(m0 + 32) * 32);
      kn1 = *(const half8*)(kL + (size_t)(m0 + 48) * 32);
      asm volatile("s_waitcnt vmcnt(6)" ::: "memory");
    } else {
      asm volatile("s_waitcnt vmcnt(0)" ::: "memory");
    }

    // S = Q K^T for this wave's 16 n x 32 m (K in regs)
    floatx4 s0 = __builtin_amdgcn_mfma_f32_16x16x32_f16(aq, kc0, zf, 0, 0, 0);
    floatx4 s1 = __builtin_amdgcn_mfma_f32_16x16x32_f16(aq, kc1, zf, 0, 0, 0);

    float p0[4], p1[4];
#pragma unroll
    for (int r = 0; r < 4; r++) {
      p0[r] = fast_exp2(s0[r] * L2E);
      p1[r] = fast_exp2(s1[r] * L2E);
      lsum[r] += p0[r] + p1[r];
    }
#pragma unroll
    for (int r = 0; r < 4; r++) {
      int row = q4 * 4 + r;
      sPw[row * 40 + l15]      = f32_to_f16u(p0[r]);
      sPw[row * 40 + 16 + l15] = f32_to_f16u(p1[r]);
    }
    asm volatile("s_waitcnt lgkmcnt(0)" ::: "memory");  // own P writes visible

    // barrier: all P written, all V(it) landed (each wave vmcnt-waited above)
    __builtin_amdgcn_s_barrier();
    asm volatile("s_waitcnt lgkmcnt(0)" ::: "memory");  // fence: no read hoist

    // P-frags for ALL 64 n (rows nt*16+l15, k = m = q4*8+j)
    half8 ap[4];
#pragma unroll
    for (int nt = 0; nt < 4; nt++)
      ap[nt] = *(const half8*)&sP[nt * 640 + l15 * 40 + q4 * 8];

    const unsigned short* sVb = (const unsigned short*)(smem + bufoff);
#pragma unroll
    for (int ct = 0; ct < 4; ct++) {
      int co = w * 64 + ct * 16 + l15;
      half8 bv8 = *(const half8*)&sVb[co * 32 + ((q4 ^ ((co >> 1) & 3)) * 8)];
#pragma unroll
      for (int nt = 0; nt < 4; nt++)
        acc[ct * 4 + nt] = __builtin_amdgcn_mfma_f32_16x16x32_f16(ap[nt], bv8, acc[ct * 4 + nt], 0, 0, 0);
    }
    asm volatile("s_waitcnt lgkmcnt(0)" ::: "memory");  // reads done before reuse
    __builtin_amdgcn_s_barrier();

    kc0 = kn0; kc1 = kn1;
    bufoff ^= 16384;
  }

  // lsum reduce (S phase split by n: wave w owns rows n0+16w+..)
#pragma unroll
  for (int off = 1; off < 16; off <<= 1) {
#pragma unroll
    for (int r = 0; r < 4; r++) lsum[r] += __shfl_xor(lsum[r], off);
  }
  if (l15 == 0) {
#pragma unroll
    for (int r = 0; r < 4; r++)
      lW[((size_t)chunk * 4 + b) * 4096 + n0 + 16 * w + q4 * 4 + r] = lsum[r];
  }

  // epilogue: wave w owns co w*64..w*64+63, all 64 n.
  unsigned short* sO = (unsigned short*)smem;  // [128 co][pitch 72]
#pragma unroll
  for (int pass = 0; pass < 2; pass++) {
    __syncthreads();
    if ((w >> 1) == pass) {
#pragma unroll
      for (int ct = 0; ct < 4; ct++) {
        int co_l = (w & 1) * 64 + ct * 16 + l15;
#pragma unroll
        for (int nt = 0; nt < 4; nt++) {
#pragma unroll
          for (int r = 0; r < 4; r++) {
            int nl = nt * 16 + q4 * 4 + r;
            sO[co_l * 72 + nl] = f32_to_f16u(acc[ct * 4 + nt][r]);
          }
        }
      }
    }
    __syncthreads();
#pragma unroll
    for (int s = 0; s < 4; s++) {
      int co_l = s * 32 + (t >> 3);
      int ch = t & 7;
      int4 val = *(const int4*)&sO[co_l * 72 + ch * 8];
      *(int4*)&Op[(((size_t)chunk * 4 + b) * 256 + pass * 128 + co_l) * 4096 + n0 + ch * 8] = val;
    }
  }
}

// ---------------------------------------------------------------------------
// Combine: out[b][co][n] = sum_ch Op[ch][b][co][n] / sum_ch lW[ch][b][n]
// ---------------------------------------------------------------------------
__global__ __launch_bounds__(256) void combine_kernel(
    const unsigned short* __restrict__ Op,
    const float* __restrict__ lW,
    float* __restrict__ out)
{
  const int t = threadIdx.x;
  const int b = blockIdx.y;
  const size_t n8 = (size_t)blockIdx.x * 2048 + (size_t)t * 8;
  const int co0 = blockIdx.z * 4;

  float sum[8] = {0.f, 0.f, 0.f, 0.f, 0.f, 0.f, 0.f, 0.f};
#pragma unroll
  for (int ch = 0; ch < 4; ch++) {
    const float* lp = lW + ((size_t)ch * 4 + b) * 4096 + n8;
    float4 a0 = *(const float4*)lp;
    float4 a1 = *(const float4*)(lp + 4);
    sum[0] += a0.x; sum[1] += a0.y; sum[2] += a0.z; sum[3] += a0.w;
    sum[4] += a1.x; sum[5] += a1.y; sum[6] += a1.z; sum[7] += a1.w;
  }
  float rl[8];
#pragma unroll
  for (int i = 0; i < 8; i++) rl[i] = 1.0f / sum[i];

#pragma unroll
  for (int cc = 0; cc < 4; cc++) {
    int co = co0 + cc;
    float o[8] = {0.f, 0.f, 0.f, 0.f, 0.f, 0.f, 0.f, 0.f};
#pragma unroll
    for (int ch = 0; ch < 4; ch++) {
      half8 hv = *(const half8*)&Op[(((size_t)ch * 4 + b) * 256 + co) * 4096 + n8];
#pragma unroll
      for (int i = 0; i < 8; i++) o[i] += (float)hv[i];
    }
    float* op = out + ((size_t)b * 256 + co) * 4096 + n8;
    float4 r0, r1;
    r0.x = o[0] * rl[0]; r0.y = o[1] * rl[1]; r0.z = o[2] * rl[2]; r0.w = o[3] * rl[3];
    r1.x = o[4] * rl[4]; r1.y = o[5] * rl[5]; r1.z = o[6] * rl[6]; r1.w = o[7] * rl[7];
    *(float4*)op = r0;
    *(float4*)(op + 4) = r1;
  }
}

extern "C" void kernel_launch(void* const* d_in, const int* in_sizes, int n_in,
                              void* d_out, int out_size, void* d_ws, size_t ws_size,
                              hipStream_t stream) {
  const float* rgb   = (const float*)d_in[0];
  const float* depth = (const float*)d_in[1];
  const float* Wq    = (const float*)d_in[2];
  const float* bq    = (const float*)d_in[3];
  const float* Wk    = (const float*)d_in[4];
  const float* bk    = (const float*)d_in[5];
  const float* Wv    = (const float*)d_in[6];
  const float* bv    = (const float*)d_in[7];
  float* out = (float*)d_out;

  unsigned short* qT = (unsigned short*)d_ws;             // 1 MB
  unsigned short* kT = qT + (size_t)4 * 4096 * 32;        // 1 MB
  unsigned short* vW = kT + (size_t)4 * 4096 * 32;        // 8 MB
  unsigned short* Op = vW + (size_t)4 * 256 * 4096;       // 33.5 MB (4 chunks)
  float* lW = (float*)(Op + (size_t)4 * 4 * 256 * 4096);  // 256 KB

  dim3 pg(64, 4, 3);
  proj_kernel<<<pg, 256, 0, stream>>>(rgb, depth, Wq, bq, Wk, bk, Wv, bv, qT, kT, vW);
  attn_kernel<<<dim3(1024, 1, 1), 256, 0, stream>>>(qT, kT, vW, Op, lW);
  dim3 cg(2, 4, 64);
  combine_kernel<<<cg, 256, 0, stream>>>(Op, lW, out);
}